// Round 8
// baseline (19062.038 us; speedup 1.0000x reference)
//
#include <hip/hip_runtime.h>
#include <math.h>

// ws layout (floats)
#define H0A_OFF  0            // [64][512] h0, step parity 0
#define H0B_OFF  32768        // [64][512] h0, step parity 1
#define H1_OFF   65536        // [64][512] h1
#define RH0_OFF  98304        // [64][512]
#define RH1_OFF  131072       // [64][512]
#define FLG_OFF  163840       // u32: arr[4 dom][64] then go[4 dom] @64B stride
#define WS_FLOATS (163840 + 512)
#define WS_BYTES  (WS_FLOATS * 4)

// LDS row stride (words). 516 % 32 == 4: rows rgl=0..7 -> 8 distinct bank
// quads -> conflict-free b128 state reads. 516 % 4 == 0 keeps 16B alignment.
#define SROW 516

__device__ __forceinline__ void gstore(float* p, float v) {
    __hip_atomic_store(p, v, __ATOMIC_RELAXED, __HIP_MEMORY_SCOPE_AGENT);
}
__device__ __forceinline__ unsigned gloadU(const unsigned* p) {
    return __hip_atomic_load(p, __ATOMIC_RELAXED, __HIP_MEMORY_SCOPE_AGENT);
}
__device__ __forceinline__ void gstoreU(unsigned* p, unsigned v) {
    __hip_atomic_store(p, v, __ATOMIC_RELAXED, __HIP_MEMORY_SCOPE_AGENT);
}
__device__ __forceinline__ float fma4(float4 w, float4 x, float a) {
    a = fmaf(w.x, x.x, a); a = fmaf(w.y, x.y, a);
    a = fmaf(w.z, x.z, a); a = fmaf(w.w, x.w, a);
    return a;
}

// Issue 4 coherent b128 loads (64 KB region across 1024 threads). Values are
// NOT valid until a vmcnt drain.
__device__ __forceinline__ void issue4(float4 t[4], const float* __restrict__ src, int tid) {
    #pragma unroll
    for (int i = 0; i < 4; ++i) {
        const float* p = src + 4 * tid + 4096 * i;
        asm volatile("global_load_dwordx4 %0, %1, off sc0 sc1"
                     : "=&v"(t[i]) : "v"(p) : "memory");
    }
}
__device__ __forceinline__ void drain_all() {
    asm volatile("s_waitcnt vmcnt(0)" ::: "memory");
}
// Wait until at most the 4 NEWEST vmem ops remain outstanding (FIFO):
// completes everything issued before them. Compiler-emitted waits can only be
// more conservative (they force extra completion), never unsafe.
__device__ __forceinline__ void drain_keep4() {
    asm volatile("s_waitcnt vmcnt(4)" ::: "memory");
}
__device__ __forceinline__ void lds_write4(float* __restrict__ buf, const float4 t[4], int tid) {
    #pragma unroll
    for (int i = 0; i < 4; ++i) {
        int f4i = tid + 1024 * i;
        int row = f4i >> 7, col4 = f4i & 127;
        *(float4*)&buf[row * SROW + col4 * 4] = t[i];
    }
}

// Per-domain 2-hop barrier (64 blocks) — protocol identical to the verified
// 18335us kernel; aggregator duty now on wave 0 of the domain's j==0 block
// (dual-duty: polls where it would otherwise idle). Arrivals: per-block flag
// STORE (distinct addrs, 4 lines). Detection: the aggregator wave polls the
// 64 arr flags (1/lane) AND the other layer's go-gate, then lane 0 publishes
// go[dom]=tag; members poll go[dom] with one scalar load. go[dom]>=tag implies
// all own arrivals >= tag and goOth >= otag. First __syncthreads drains each
// wave's vmem (HIP barrier semantics) -> data stores for this phase are at the
// coherence point before the arrival store. Tags monotonic, never reset.
__device__ __forceinline__ void gbar(unsigned* arrD, unsigned* goOwn,
                                     const unsigned* goOth, int myIdx, bool agg,
                                     int tid, unsigned tag, unsigned otag) {
    __syncthreads();
    if (agg) {
        if (tid < 64) {
            if (tid == 0) gstoreU(arrD + myIdx, tag);
            for (;;) {
                bool ok = ((int)(gloadU(arrD + tid) - tag) >= 0) &&
                          ((int)(gloadU(goOth) - otag) >= 0);
                if (__ballot(ok) == ~0ull) break;
                __builtin_amdgcn_s_sleep(2);
            }
            if (tid == 0) gstoreU(goOwn, tag);
        }
    } else if (tid == 0) {
        gstoreU(arrD + myIdx, tag);
        while ((int)(gloadU(goOwn) - tag) < 0)
            __builtin_amdgcn_s_sleep(2);
    }
    __syncthreads();
}

__global__ __launch_bounds__(1024, 1) void gru_main(
    const int* __restrict__ tokens, const float* __restrict__ emb,
    const float* __restrict__ Wr0, const float* __restrict__ br0,
    const float* __restrict__ Wz0, const float* __restrict__ bz0,
    const float* __restrict__ Wh0, const float* __restrict__ bh0,
    const float* __restrict__ Wr1, const float* __restrict__ br1,
    const float* __restrict__ Wz1, const float* __restrict__ bz1,
    const float* __restrict__ Wh1, const float* __restrict__ bh1,
    float* __restrict__ ws)
{
    const int blk = blockIdx.x;
    const int tid = threadIdx.x;

    // XCD = blk%8 = rg*4 + jl -> per-XCD weight footprint L2-resident.
    const int rg    = (blk >> 2) & 1;
    const int jl    = blk & 3;
    const int jh    = (blk >> 3) & 15;
    const int layer = blk >> 7;
    const int j     = jh * 4 + jl;
    const int wave  = tid >> 6;           // 16 compute waves
    const int ks    = wave & 7;           // k-slice (identical to verified)
    const int rrh   = (wave >> 3) & 1;    // rr-half: rr = 2*rrh + q, q in {0,1}
    const int lane  = tid & 63;
    const int c     = lane >> 3;
    const int rgl   = lane & 7;
    const int rowbase = rg * 32;
    const int cg    = j * 8 + c;
    const int cR    = (tid >> 5) & 7;     // reducer col (tid<256 only)
    const int riR   = tid & 31;           // reducer row
    const int cgR   = j * 8 + cR;

    // Barrier domains: dom = layer*2 + rg (64 blocks each). L0<->L1 coupling
    // elastic via go-gates (verbatim from verified kernel) + h0 parity dbuf.
    unsigned* flg  = (unsigned*)(ws + FLG_OFF);
    const int dom  = layer * 2 + rg;
    const int odom = (layer ? 0 : 2) + rg;     // other layer, same rg
    unsigned* arrD  = flg + dom * 64;
    unsigned* goOwn = flg + 256 + dom * 16;    // 64 B apart
    unsigned* goOth = flg + 256 + odom * 16;
    const bool agg  = (j == 0);                // one aggregator block per domain

    const int S1 = layer ? 512 : 256;
    const int K  = S1 + 512;
    const float* WrL = layer ? Wr1 : Wr0;
    const float* WzL = layer ? Wz1 : Wz0;
    const float* WhL = layer ? Wh1 : Wh0;
    const float* wrRow = WrL + (size_t)cg * K;
    const float* wzRow = WzL + (size_t)cg * K;
    const float* whRow = WhL + (size_t)cg * K;
    const float bR = (layer ? br1 : br0)[cgR];
    const float bZ = (layer ? bz1 : bz0)[cgR];
    const float bH = (layer ? bh1 : bh0)[cgR];

    // h0 double-buffered by step parity: L0 writes h0buf[s&1] at iter s, reads
    // h0buf[(s-1)&1]; L1 stages h0buf[(s-1)&1] as seg1 input. (Verified.)
    const float* h0buf[2] = { ws + H0A_OFF, ws + H0B_OFF };
    float* h0bufW[2] = { ws + H0A_OFF, ws + H0B_OFF };
    float* h1p   = ws + H1_OFF;
    float* rhOwn = ws + (layer ? RH1_OFF : RH0_OFF);

    __shared__ float  bufA[32 * SROW];    // 66,048 B  (x -> h_prev -> rh)
    __shared__ float  pTmp[3 * 2048];     // 24,576 B  (8 k-slices x 256 x 3)
    __shared__ float4 wLDS[3072];         // 49,152 B  seg2 weights [gate][chunk][col]

    // ---- one-time: seg2 weights (own 8 cols, 3 gates) -> LDS ----
    {
        const float* Wb[3] = {WrL, WzL, WhL};
        for (int idx = tid; idx < 3072; idx += 1024) {
            int g = idx >> 10, rem = idx & 1023, chunk = rem >> 3, c8 = rem & 7;
            wLDS[(g * 128 + chunk) * 8 + c8] =
                *(const float4*)(Wb[g] + (size_t)(j * 8 + c8) * K + S1 + 4 * chunk);
        }
    }

    const int k1  = ks * (S1 >> 3);       // seg1 wave base (8-way k-split)
    const int k2s = ks * 64;              // seg2 wave base (state coords)
    const int wch = ks * 16;              // seg2 wave base (wLDS chunk coords)
    const int nq1 = S1 >> 5;              // seg1 f4-iters per wave (L0:8, L1:16)

    for (int s = 0; s <= 1024; ++s) {
        const bool act = layer ? (s >= 1) : (s < 1024);
        float zv = 0.f, hp = 0.f, hx = 0.f;
        float aR[2] = {0,0}, aZ[2] = {0,0}, aH[2] = {0,0};
        float4 hpv[4];

        const float* hReadP = layer ? (const float*)h1p : h0buf[(s - 1) & 1];
        const float* hInP   = h0buf[(s - 1) & 1];   // L1 seg1 input

        // ---- phase A: stage x -> bufA (drained) + prefetch h_prev (in flight) ----
        if (act) {
            if (layer) {
                float4 t[4];
                issue4(t, hInP + rowbase * 512, tid);      // oldest 4
                issue4(hpv, hReadP + rowbase * 512, tid);  // newest 4
                drain_keep4();                             // x done, hpv in flight
                lds_write4(bufA, t, tid);
            } else {
                float4 t[2];
                #pragma unroll
                for (int q = 0; q < 2; ++q) {              // emb gather (oldest)
                    int f4i = tid + 1024 * q;
                    int row = f4i >> 6, col4 = f4i & 63;
                    int tok = tokens[(rowbase + row) * 1024 + s];
                    t[q] = *(const float4*)(emb + (size_t)tok * 256 + col4 * 4);
                }
                issue4(hpv, hReadP + rowbase * 512, tid);  // newest 4
                drain_keep4();                             // emb done, hpv in flight
                #pragma unroll
                for (int q = 0; q < 2; ++q) {
                    int f4i = tid + 1024 * q;
                    int row = f4i >> 6, col4 = f4i & 63;
                    *(float4*)&bufA[row * SROW + col4 * 4] = t[q];
                }
            }
        }
        __syncthreads();

        // ---- dot seg1 (x in bufA; weights stream from L2; h_prev in flight) ----
        if (act) {
            #pragma unroll 4
            for (int i = 0; i < nq1; ++i) {
                int kk = k1 + 4 * i;
                float4 w1 = *(const float4*)(wrRow + kk);
                float4 w2 = *(const float4*)(wzRow + kk);
                float4 w3 = *(const float4*)(whRow + kk);
                #pragma unroll
                for (int q = 0; q < 2; ++q) {
                    int rr = 2 * rrh + q;
                    float4 xv = *(const float4*)(&bufA[(rgl + 8 * rr) * SROW + kk]);
                    aR[q] = fma4(w1, xv, aR[q]);
                    aZ[q] = fma4(w2, xv, aZ[q]);
                    aH[q] = fma4(w3, xv, aH[q]);
                }
            }
        }
        __syncthreads();                  // all waves done reading seg1

        if (act) {
            drain_all();                  // h_prev arrived during seg1 dot
            lds_write4(bufA, hpv, tid);
        }
        __syncthreads();

        // ---- dot seg2: r,z from LDS weights (h_prev in bufA) ----
        if (act) {
            #pragma unroll 4
            for (int i = 0; i < 16; ++i) {
                int kst = k2s + 4 * i;
                float4 w1 = wLDS[(wch + i) * 8 + c];
                float4 w2 = wLDS[(128 + wch + i) * 8 + c];
                #pragma unroll
                for (int q = 0; q < 2; ++q) {
                    int rr = 2 * rrh + q;
                    float4 xv = *(const float4*)(&bufA[(rgl + 8 * rr) * SROW + kst]);
                    aR[q] = fma4(w1, xv, aR[q]);
                    aZ[q] = fma4(w2, xv, aZ[q]);
                }
            }
            #pragma unroll
            for (int q = 0; q < 2; ++q) {
                int o = ks * 256 + c * 32 + (rgl + 8 * (2 * rrh + q));
                pTmp[o]        = aR[q];
                pTmp[2048 + o] = aZ[q];
                pTmp[4096 + o] = aH[q];
            }
        }
        __syncthreads();

        // ---- R1: reduce + activations + publish rh (256 reducer threads) ----
        if (act && tid < 256) {
            int o = cR * 32 + riR;
            float sR = 0.f, sZ = 0.f, sH = 0.f;
            #pragma unroll
            for (int p = 0; p < 8; ++p) {
                sR += pTmp[o + 256 * p];
                sZ += pTmp[2048 + o + 256 * p];
                sH += pTmp[4096 + o + 256 * p];
            }
            float rv = 1.f / (1.f + expf(-(sR + bR)));
            zv = 1.f / (1.f + expf(-(sZ + bZ)));
            hx = sH;
            hp = bufA[riR * SROW + cgR];          // bufA still holds h_prev
            gstore(rhOwn + (rowbase + riR) * 512 + cgR, rv * hp);
        }

        // ---- b1(s) (tag 2s+1): rh exchange. Gates verbatim from verified. ----
        gbar(arrD, goOwn, goOth, j, agg, tid, (unsigned)(2 * s + 1),
             (!layer && s >= 2) ? (unsigned)(2 * s - 1) : 0u);

        // ---- P2: stage rh -> bufA; h-gate recurrent dot ----
        if (act) {
            float4 trh[4];
            issue4(trh, rhOwn + rowbase * 512, tid);
            drain_all();
            lds_write4(bufA, trh, tid);
        }
        __syncthreads();

        if (act) {
            float a3[2] = {0,0};
            #pragma unroll 4
            for (int i = 0; i < 16; ++i) {
                int kst = k2s + 4 * i;
                float4 w3 = wLDS[(256 + wch + i) * 8 + c];
                #pragma unroll
                for (int q = 0; q < 2; ++q) {
                    int rr = 2 * rrh + q;
                    float4 xv = *(const float4*)(&bufA[(rgl + 8 * rr) * SROW + kst]);
                    a3[q] = fma4(w3, xv, a3[q]);
                }
            }
            #pragma unroll
            for (int q = 0; q < 2; ++q)
                pTmp[ks * 256 + c * 32 + (rgl + 8 * (2 * rrh + q))] = a3[q];
        }
        __syncthreads();

        // ---- R2: reduce + tanh + publish h[s] ----
        if (act && tid < 256) {
            float* hWriteP = layer ? h1p : h0bufW[s & 1];
            int o = cR * 32 + riR;
            float sH2 = 0.f;
            #pragma unroll
            for (int p = 0; p < 8; ++p) sH2 += pTmp[o + 256 * p];
            float ht = tanhf(hx + sH2 + bH);
            float hn = (1.f - zv) * hp + zv * ht;
            gstore(hWriteP + (rowbase + riR) * 512 + cgR, hn);
        }

        // ---- b2(s) (tag 2s+2): h exchange. Gates verbatim from verified. ----
        gbar(arrD, goOwn, goOth, j, agg, tid, (unsigned)(2 * s + 2),
             layer ? (unsigned)(2 * s + 2) : 0u);
    }
}

__global__ __launch_bounds__(128) void gru_fc(
    const float* __restrict__ h1f, const float* __restrict__ fcW,
    const float* __restrict__ fcb, float* __restrict__ out)
{
    int tid = threadIdx.x;
    int b = tid >> 1, cc = tid & 1;
    const float* hrow = h1f + b * 512;
    const float* wrow = fcW + cc * 512;
    float acc = 0.f;
    #pragma unroll 4
    for (int k = 0; k < 512; k += 4) {
        float4 hv = *(const float4*)(hrow + k);
        float4 wv = *(const float4*)(wrow + k);
        acc = fmaf(hv.x, wv.x, fmaf(hv.y, wv.y, fmaf(hv.z, wv.z, fmaf(hv.w, wv.w, acc))));
    }
    out[b * 2 + cc] = acc + fcb[cc];
}

extern "C" void kernel_launch(void* const* d_in, const int* in_sizes, int n_in,
                              void* d_out, int out_size, void* d_ws, size_t ws_size,
                              hipStream_t stream) {
    const int* tokens = (const int*)d_in[0];
    const float* emb = (const float*)d_in[1];
    const float* Wr0 = (const float*)d_in[2];  const float* br0 = (const float*)d_in[3];
    const float* Wz0 = (const float*)d_in[4];  const float* bz0 = (const float*)d_in[5];
    const float* Wh0 = (const float*)d_in[6];  const float* bh0 = (const float*)d_in[7];
    const float* Wr1 = (const float*)d_in[8];  const float* br1 = (const float*)d_in[9];
    const float* Wz1 = (const float*)d_in[10]; const float* bz1 = (const float*)d_in[11];
    const float* Wh1 = (const float*)d_in[12]; const float* bh1 = (const float*)d_in[13];
    const float* fcW = (const float*)d_in[14]; const float* fcb = (const float*)d_in[15];
    float* ws = (float*)d_ws;

    hipMemsetAsync(d_ws, 0, WS_BYTES, stream);

    gru_main<<<256, 1024, 0, stream>>>(tokens, emb, Wr0, br0, Wz0, bz0, Wh0, bh0,
                                       Wr1, br1, Wz1, bz1, Wh1, bh1, ws);
    gru_fc<<<1, 128, 0, stream>>>(ws + H1_OFF, fcW, fcb, (float*)d_out);
}

// Round 10
// 14716.931 us; speedup vs baseline: 1.2952x; 1.2952x over previous
//
#include <hip/hip_runtime.h>
#include <math.h>

// ws layout (floats)
#define H0A_OFF  0            // [64][512] h0, step parity 0
#define H0B_OFF  32768        // [64][512] h0, step parity 1
#define H1_OFF   65536        // [64][512] h1
#define RH0_OFF  98304        // [64][512]
#define RH1_OFF  131072       // [64][512]
#define FLG_OFF  163840       // u32: arr[4 dom][64] then go[4 dom] @64B stride
#define WS_FLOATS (163840 + 512)
#define WS_BYTES  (WS_FLOATS * 4)

// LDS row stride (words). 516 % 32 == 4: rows rgl=0..7 -> 8 distinct bank
// quads -> conflict-free b128 state reads. 516 % 4 == 0 keeps 16B alignment.
#define SROW 516

__device__ __forceinline__ void gstore(float* p, float v) {
    __hip_atomic_store(p, v, __ATOMIC_RELAXED, __HIP_MEMORY_SCOPE_AGENT);
}
__device__ __forceinline__ unsigned gloadU(const unsigned* p) {
    return __hip_atomic_load(p, __ATOMIC_RELAXED, __HIP_MEMORY_SCOPE_AGENT);
}
__device__ __forceinline__ void gstoreU(unsigned* p, unsigned v) {
    __hip_atomic_store(p, v, __ATOMIC_RELAXED, __HIP_MEMORY_SCOPE_AGENT);
}
__device__ __forceinline__ float fma4(float4 w, float4 x, float a) {
    a = fmaf(w.x, x.x, a); a = fmaf(w.y, x.y, a);
    a = fmaf(w.z, x.z, a); a = fmaf(w.w, x.w, a);
    return a;
}

// Per-wave 64-col slice (32 rows x 64 cols, 8 KB) of a [32][512] global
// region: issue 8 coherent b128 loads. NOT valid until a vmcnt drain.
// Mapping: f4i = lane + 64*i -> rowL = f4i>>4, c4 = f4i&15.
__device__ __forceinline__ void issueSlice(float4 t[8], const float* __restrict__ src,
                                           int lane, int cbase) {
    #pragma unroll
    for (int i = 0; i < 8; ++i) {
        int f4i = lane + 64 * i, rowL = f4i >> 4, c4 = f4i & 15;
        const float* p = src + rowL * 512 + cbase + 4 * c4;
        asm volatile("global_load_dwordx4 %0, %1, off sc0 sc1"
                     : "=&v"(t[i]) : "v"(p) : "memory");
    }
}
__device__ __forceinline__ void writeSlice(float* __restrict__ buf, const float4 t[8],
                                           int lane, int cbase) {
    #pragma unroll
    for (int i = 0; i < 8; ++i) {
        int f4i = lane + 64 * i, rowL = f4i >> 4, c4 = f4i & 15;
        *(float4*)&buf[rowL * SROW + cbase + 4 * c4] = t[i];
    }
}
__device__ __forceinline__ void drain_all() {
    asm volatile("s_waitcnt vmcnt(0)" ::: "memory");
}
// Wait until at most the 8 NEWEST vmem ops of THIS WAVE remain outstanding
// (FIFO): completes everything issued before them. Compiler-emitted waits can
// only be more conservative, never unsafe.
__device__ __forceinline__ void drain_keep8() {
    asm volatile("s_waitcnt vmcnt(8)" ::: "memory");
}

// Per-domain 2-hop barrier (64 blocks) — protocol verbatim from the verified
// 18335us kernel; aggregator duty on wave 0 of the domain's j==0 block
// (dual-duty, R8-verified). Arrivals: per-block flag STORE (distinct addrs,
// 4 lines). Detection: aggregator wave polls 64 arr flags (1/lane) AND the
// other layer's go-gate, then lane 0 publishes go[dom]=tag; members poll
// go[dom] with one scalar load. First __syncthreads drains each wave's vmem
// (HIP barrier semantics) -> data stores for this phase are at the coherence
// point before the arrival store. Tags monotonic, never reset.
__device__ __forceinline__ void gbar(unsigned* arrD, unsigned* goOwn,
                                     const unsigned* goOth, int myIdx, bool agg,
                                     int tid, unsigned tag, unsigned otag) {
    __syncthreads();
    if (agg) {
        if (tid < 64) {
            if (tid == 0) gstoreU(arrD + myIdx, tag);
            for (;;) {
                bool ok = ((int)(gloadU(arrD + tid) - tag) >= 0) &&
                          ((int)(gloadU(goOth) - otag) >= 0);
                if (__ballot(ok) == ~0ull) break;
                __builtin_amdgcn_s_sleep(2);
            }
            if (tid == 0) gstoreU(goOwn, tag);
        }
    } else if (tid == 0) {
        gstoreU(arrD + myIdx, tag);
        while ((int)(gloadU(goOwn) - tag) < 0)
            __builtin_amdgcn_s_sleep(2);
    }
    __syncthreads();
}

__global__ __launch_bounds__(512, 1) void gru_main(
    const int* __restrict__ tokens, const float* __restrict__ emb,
    const float* __restrict__ Wr0, const float* __restrict__ br0,
    const float* __restrict__ Wz0, const float* __restrict__ bz0,
    const float* __restrict__ Wh0, const float* __restrict__ bh0,
    const float* __restrict__ Wr1, const float* __restrict__ br1,
    const float* __restrict__ Wz1, const float* __restrict__ bz1,
    const float* __restrict__ Wh1, const float* __restrict__ bh1,
    float* __restrict__ ws)
{
    const int blk = blockIdx.x;
    const int tid = threadIdx.x;

    // XCD = blk%8 = rg*4 + jl -> per-XCD weight footprint L2-resident.
    const int rg    = (blk >> 2) & 1;
    const int jl    = blk & 3;
    const int jh    = (blk >> 3) & 15;
    const int layer = blk >> 7;
    const int j     = jh * 4 + jl;
    const int ks    = tid >> 6;           // 8 waves, wave = k-slice (R5 mapping)
    const int lane  = tid & 63;
    const int c     = lane >> 3;
    const int rgl   = lane & 7;
    const int rowbase = rg * 32;
    const int cg    = j * 8 + c;
    const int cR    = (tid >> 5) & 7;     // reducer col (tid<256 only)
    const int riR   = tid & 31;           // reducer row
    const int cgR   = j * 8 + cR;

    // Barrier domains: dom = layer*2 + rg (64 blocks each). L0<->L1 coupling
    // elastic via go-gates (verbatim) + h0 parity double-buffer.
    unsigned* flg  = (unsigned*)(ws + FLG_OFF);
    const int dom  = layer * 2 + rg;
    const int odom = (layer ? 0 : 2) + rg;     // other layer, same rg
    unsigned* arrD  = flg + dom * 64;
    unsigned* goOwn = flg + 256 + dom * 16;    // 64 B apart
    unsigned* goOth = flg + 256 + odom * 16;
    const bool agg  = (j == 0);                // one aggregator block per domain

    const int S1 = layer ? 512 : 256;
    const int K  = S1 + 512;
    const float* WrL = layer ? Wr1 : Wr0;
    const float* WzL = layer ? Wz1 : Wz0;
    const float* WhL = layer ? Wh1 : Wh0;
    const float* wrRow = WrL + (size_t)cg * K;
    const float* wzRow = WzL + (size_t)cg * K;
    const float* whRow = WhL + (size_t)cg * K;
    const float bR = (layer ? br1 : br0)[cgR];
    const float bZ = (layer ? bz1 : bz0)[cgR];
    const float bH = (layer ? bh1 : bh0)[cgR];

    // h0 double-buffered by step parity (verified protocol).
    const float* h0buf[2] = { ws + H0A_OFF, ws + H0B_OFF };
    float* h0bufW[2] = { ws + H0A_OFF, ws + H0B_OFF };
    float* h1p   = ws + H1_OFF;
    float* rhOwn = ws + (layer ? RH1_OFF : RH0_OFF);

    // bufA = x only (wave-private col slices for the whole iteration)
    // bufB = h_prev -> rh (wave-private col slices; cross-wave reads only in
    //        R1's hp, behind the pre-reduce __syncthreads)
    __shared__ float bufA[32 * SROW];    // 66,048 B
    __shared__ float bufB[32 * SROW];    // 66,048 B
    __shared__ float pTmp[3 * 2048];     // 24,576 B   total 156,672 B

    const int k1     = ks * (S1 >> 3);    // seg1 wave col base (L0:32w, L1:64w)
    const int k2s    = ks * 64;           // seg2/D3 wave col base (state)
    const int k2base = S1 + k2s;          // seg2/D3 weight col base
    const int nq1    = S1 >> 5;           // seg1 f4-iters (L0:8, L1:16)

    for (int s = 0; s <= 1024; ++s) {
        const bool act = layer ? (s >= 1) : (s < 1024);
        float zv = 0.f, hp = 0.f, hx = 0.f;
        float aR[4] = {0,0,0,0}, aZ[4] = {0,0,0,0}, aH[4] = {0,0,0,0};

        // ---- phase A (wave-private): stage x slice (drained) + h_prev slice
        //      (left in flight under seg1 dot). No __syncthreads needed:
        //      each wave reads only the LDS cols it wrote. ----
        if (act) {
            const float* hReadP = layer ? (const float*)h1p : h0buf[(s - 1) & 1];
            float4 thp[8];
            if (layer) {
                float4 tx[8];
                issueSlice(tx, h0buf[(s - 1) & 1] + rowbase * 512, lane, k1);  // x=h0[s-1]
                issueSlice(thp, hReadP + rowbase * 512, lane, k2s);            // newest 8
                drain_keep8();                             // x done, thp in flight
                writeSlice(bufA, tx, lane, k1);
            } else {
                float4 tx[4];
                #pragma unroll
                for (int i = 0; i < 4; ++i) {              // emb gather (32x32 slice)
                    int f4i = lane + 64 * i, rowL = f4i >> 3, c4 = f4i & 7;
                    int tok = tokens[(rowbase + rowL) * 1024 + s];
                    tx[i] = *(const float4*)(emb + (size_t)tok * 256 + k1 + 4 * c4);
                }
                issueSlice(thp, hReadP + rowbase * 512, lane, k2s);            // newest 8
                drain_keep8();                             // emb done, thp in flight
                #pragma unroll
                for (int i = 0; i < 4; ++i) {
                    int f4i = lane + 64 * i, rowL = f4i >> 3, c4 = f4i & 7;
                    *(float4*)&bufA[rowL * SROW + k1 + 4 * c4] = tx[i];
                }
            }

            // ---- seg1 dot: x slice in bufA; weights stream from L2;
            //      h_prev loads still in flight ----
            #pragma unroll 4
            for (int i = 0; i < nq1; ++i) {
                int kk = k1 + 4 * i;
                float4 w1 = *(const float4*)(wrRow + kk);
                float4 w2 = *(const float4*)(wzRow + kk);
                float4 w3 = *(const float4*)(whRow + kk);
                #pragma unroll
                for (int rr = 0; rr < 4; ++rr) {
                    float4 xv = *(const float4*)(&bufA[(rgl + 8 * rr) * SROW + kk]);
                    aR[rr] = fma4(w1, xv, aR[rr]);
                    aZ[rr] = fma4(w2, xv, aZ[rr]);
                    aH[rr] = fma4(w3, xv, aH[rr]);
                }
            }

            drain_all();                                   // h_prev slice arrived
            writeSlice(bufB, thp, lane, k2s);

            // ---- seg2: r,z recurrent dot; weights from L2 (same values and
            //      accumulation order as the verified wLDS path) ----
            #pragma unroll 4
            for (int i = 0; i < 16; ++i) {
                int kw  = k2base + 4 * i;
                int kst = k2s + 4 * i;
                float4 w1 = *(const float4*)(wrRow + kw);
                float4 w2 = *(const float4*)(wzRow + kw);
                #pragma unroll
                for (int rr = 0; rr < 4; ++rr) {
                    float4 xv = *(const float4*)(&bufB[(rgl + 8 * rr) * SROW + kst]);
                    aR[rr] = fma4(w1, xv, aR[rr]);
                    aZ[rr] = fma4(w2, xv, aZ[rr]);
                }
            }
            #pragma unroll
            for (int rr = 0; rr < 4; ++rr) {
                int o = ks * 256 + c * 32 + (rgl + 8 * rr);
                pTmp[o]        = aR[rr];
                pTmp[2048 + o] = aZ[rr];
                pTmp[4096 + o] = aH[rr];
            }
        }
        __syncthreads();

        // ---- R1: reduce + activations + publish rh ----
        if (act && tid < 256) {
            int o = cR * 32 + riR;
            float sR = 0.f, sZ = 0.f, sH = 0.f;
            #pragma unroll
            for (int p = 0; p < 8; ++p) {
                sR += pTmp[o + 256 * p];
                sZ += pTmp[2048 + o + 256 * p];
                sH += pTmp[4096 + o + 256 * p];
            }
            float rv = 1.f / (1.f + expf(-(sR + bR)));
            zv = 1.f / (1.f + expf(-(sZ + bZ)));
            hx = sH;
            hp = bufB[riR * SROW + cgR];          // bufB holds h_prev
            gstore(rhOwn + (rowbase + riR) * 512 + cgR, rv * hp);
        }

        // ---- b1(s) (tag 2s+1): rh exchange. Gates verbatim from verified. ----
        gbar(arrD, goOwn, goOth, j, agg, tid, (unsigned)(2 * s + 1),
             (!layer && s >= 2) ? (unsigned)(2 * s - 1) : 0u);

        // ---- P2 (wave-private): stage rh slice, D3 h-gate dot ----
        if (act) {
            float4 trh[8];
            issueSlice(trh, rhOwn + rowbase * 512, lane, k2s);
            drain_all();
            writeSlice(bufB, trh, lane, k2s);
            float a3[4] = {0,0,0,0};
            #pragma unroll 4
            for (int i = 0; i < 16; ++i) {
                int kw  = k2base + 4 * i;
                int kst = k2s + 4 * i;
                float4 w3 = *(const float4*)(whRow + kw);
                #pragma unroll
                for (int rr = 0; rr < 4; ++rr) {
                    float4 xv = *(const float4*)(&bufB[(rgl + 8 * rr) * SROW + kst]);
                    a3[rr] = fma4(w3, xv, a3[rr]);
                }
            }
            #pragma unroll
            for (int rr = 0; rr < 4; ++rr)
                pTmp[ks * 256 + c * 32 + (rgl + 8 * rr)] = a3[rr];
        }
        __syncthreads();

        // ---- R2: reduce + tanh + publish h[s] ----
        if (act && tid < 256) {
            float* hWriteP = layer ? h1p : h0bufW[s & 1];
            int o = cR * 32 + riR;
            float sH2 = 0.f;
            #pragma unroll
            for (int p = 0; p < 8; ++p) sH2 += pTmp[o + 256 * p];
            float ht = tanhf(hx + sH2 + bH);
            float hn = (1.f - zv) * hp + zv * ht;
            gstore(hWriteP + (rowbase + riR) * 512 + cgR, hn);
        }

        // ---- b2(s) (tag 2s+2): h exchange. Gates verbatim from verified. ----
        gbar(arrD, goOwn, goOth, j, agg, tid, (unsigned)(2 * s + 2),
             layer ? (unsigned)(2 * s + 2) : 0u);
    }
}

__global__ __launch_bounds__(128) void gru_fc(
    const float* __restrict__ h1f, const float* __restrict__ fcW,
    const float* __restrict__ fcb, float* __restrict__ out)
{
    int tid = threadIdx.x;
    int b = tid >> 1, cc = tid & 1;
    const float* hrow = h1f + b * 512;
    const float* wrow = fcW + cc * 512;
    float acc = 0.f;
    #pragma unroll 4
    for (int k = 0; k < 512; k += 4) {
        float4 hv = *(const float4*)(hrow + k);
        float4 wv = *(const float4*)(wrow + k);
        acc = fmaf(hv.x, wv.x, fmaf(hv.y, wv.y, fmaf(hv.z, wv.z, fmaf(hv.w, wv.w, acc))));
    }
    out[b * 2 + cc] = acc + fcb[cc];
}

extern "C" void kernel_launch(void* const* d_in, const int* in_sizes, int n_in,
                              void* d_out, int out_size, void* d_ws, size_t ws_size,
                              hipStream_t stream) {
    const int* tokens = (const int*)d_in[0];
    const float* emb = (const float*)d_in[1];
    const float* Wr0 = (const float*)d_in[2];  const float* br0 = (const float*)d_in[3];
    const float* Wz0 = (const float*)d_in[4];  const float* bz0 = (const float*)d_in[5];
    const float* Wh0 = (const float*)d_in[6];  const float* bh0 = (const float*)d_in[7];
    const float* Wr1 = (const float*)d_in[8];  const float* br1 = (const float*)d_in[9];
    const float* Wz1 = (const float*)d_in[10]; const float* bz1 = (const float*)d_in[11];
    const float* Wh1 = (const float*)d_in[12]; const float* bh1 = (const float*)d_in[13];
    const float* fcW = (const float*)d_in[14]; const float* fcb = (const float*)d_in[15];
    float* ws = (float*)d_ws;

    hipMemsetAsync(d_ws, 0, WS_BYTES, stream);

    gru_main<<<256, 512, 0, stream>>>(tokens, emb, Wr0, br0, Wz0, bz0, Wh0, bh0,
                                      Wr1, br1, Wz1, bz1, Wh1, bh1, ws);
    gru_fc<<<1, 128, 0, stream>>>(ws + H1_OFF, fcW, fcb, (float*)d_out);
}